// Round 6
// baseline (196.103 us; speedup 1.0000x reference)
//
#include <hip/hip_runtime.h>

#define DK 256   // feature dim (K)
#define TT 1024  // T1 = T2
#define NB 16    // batch

typedef __attribute__((ext_vector_type(8))) short bf16x8;
typedef __attribute__((ext_vector_type(4))) float f32x4;

// round-to-nearest-even fp32 -> bf16 (inputs are finite normals)
__device__ __forceinline__ unsigned short f2bf(float f) {
    unsigned int u = __float_as_uint(f);
    unsigned int r = 0x7fffu + ((u >> 16) & 1u);
    return (unsigned short)((u + r) >> 16);
}
__device__ __forceinline__ unsigned int pack2(float a, float b) {
    return (unsigned int)f2bf(a) | ((unsigned int)f2bf(b) << 16);
}
__device__ __forceinline__ bf16x8 cvt8(const float4 a, const float4 b) {
    union { unsigned int u[4]; bf16x8 v; } r;
    r.u[0] = pack2(a.x, a.y); r.u[1] = pack2(a.z, a.w);
    r.u[2] = pack2(b.x, b.y); r.u[3] = pack2(b.z, b.w);
    return r.v;
}

// ---------------------------------------------------------------------------
// Fully fused: out[b,i,j] = sum_k bf16(x)[b,i,k]*bf16(w3*y)[b,j,k]
//                           + (x.w1)[b,i] + (y.w2)[b,j]
//
// R6 vs R5 (kernel was latency-bound at 16 waves/CU, LDS-capped):
//  * B-tile halved to 128j x 128k (32 KB LDS), 2-phase K-loop (2 extra
//    barriers). Wave owns 16 i-rows (acc[8] = 32 VGPRs).
//  * __launch_bounds__(512, 6): VGPR cap 85 -> 3 blocks x 8 waves =
//    24 waves/CU (was 16). Gain was ~linear in waves R4->R5.
//  * Block swizzle: id = jt*128 + b*8 + is -> blocks sharing (b,is)
//    [the 8 jt variants re-reading the same x-slice] have equal id%8 ->
//    same XCD; per-XCD x slice set = 2.1 MB < 4 MB L2 -> x re-reads L2-hit.
//  * Non-temporal out stores: 64 MB of writes don't evict x/y from L2/L3.
//  * XOR-swizzled LDS (slot = chunk ^ (j&7)): staging writes and fragment
//    ds_read_b128 both <=2 lanes/bank (free, m136).
// ---------------------------------------------------------------------------
__global__ __launch_bounds__(512, 6) void fused_kernel(
    const float* __restrict__ x, const float* __restrict__ y,
    const float* __restrict__ WS, float* __restrict__ out)
{
    __shared__ unsigned short Bs[128 * 128];   // 32 KB
    __shared__ float tys[128];

    const int tid  = threadIdx.x;
    const int lane = tid & 63;
    const int w    = tid >> 6;                // wave 0..7

    const int id = blockIdx.x;                // 0..1023
    const int jt = id >> 7;                   // j tile (0..7), 128 cols
    const int b  = (id >> 3) & 15;            // batch
    const int is = id & 7;                    // i slice (0..7), 128 rows

    const int mfr  = lane & 15;
    const int quad = lane >> 4;

    const float* gY0 = y + ((size_t)b * TT + jt * 128) * DK;
    const float* gA0 = x + ((size_t)b * TT + is * 128 + w * 16 + mfr) * DK;

    const int sj = tid >> 4;                  // staging: row within 32-group
    const int sc = tid & 15;                  // staging: 16B chunk in row-half

    f32x4 acc[8];
    #pragma unroll
    for (int n = 0; n < 8; ++n)
        acc[n] = (f32x4){0.f, 0.f, 0.f, 0.f};
    float txp = 0.f;

    #pragma unroll
    for (int kh = 0; kh < 2; ++kh) {
        if (kh) __syncthreads();              // all waves done reading phase 0

        // ---- stage B = bf16(w3*y) for this K-half, accumulate ty = y.w2
        #pragma unroll
        for (int q = 0; q < 4; ++q) {
            const int j = q * 32 + sj;        // local y row 0..127
            const float* src = gY0 + (size_t)j * DK + kh * 128 + sc * 8;
            const float* w3p = WS + 2 * DK + kh * 128 + sc * 8;
            const float* w2p = WS + DK + kh * 128 + sc * 8;
            const float4 ya = *(const float4*)(src);
            const float4 yb = *(const float4*)(src + 4);
            const float4 wa = *(const float4*)(w3p);
            const float4 wb = *(const float4*)(w3p + 4);
            const float4 va = *(const float4*)(w2p);
            const float4 vb = *(const float4*)(w2p + 4);
            float p = ya.x * va.x + ya.y * va.y + ya.z * va.z + ya.w * va.w
                    + yb.x * vb.x + yb.y * vb.y + yb.z * vb.z + yb.w * vb.w;
            const float4 pa = make_float4(ya.x * wa.x, ya.y * wa.y,
                                          ya.z * wa.z, ya.w * wa.w);
            const float4 pb = make_float4(yb.x * wb.x, yb.y * wb.y,
                                          yb.z * wb.z, yb.w * wb.w);
            const bf16x8 o = cvt8(pa, pb);
            const int slot = sc ^ (j & 7);
            *(bf16x8*)(Bs + j * 128 + slot * 8) = o;
            // reduce p across the 16 lanes sharing row j
            p += __shfl_xor(p, 1);
            p += __shfl_xor(p, 2);
            p += __shfl_xor(p, 4);
            p += __shfl_xor(p, 8);
            if (sc == 0) {
                if (kh) tys[j] += p; else tys[j] = p;
            }
        }
        __syncthreads();

        // ---- compute this K-half: 4 MFMA K-steps of 32
        #pragma unroll
        for (int ks = 0; ks < 4; ++ks) {
            const int k0 = kh * 128 + ks * 32 + quad * 8;
            const float4 xa = *(const float4*)(gA0 + k0);
            const float4 xb = *(const float4*)(gA0 + k0 + 4);
            const float4 w1a = *(const float4*)(WS + k0);
            const float4 w1b = *(const float4*)(WS + k0 + 4);
            txp += xa.x * w1a.x + xa.y * w1a.y + xa.z * w1a.z + xa.w * w1a.w
                 + xb.x * w1b.x + xb.y * w1b.y + xb.z * w1b.z + xb.w * w1b.w;
            const bf16x8 av = cvt8(xa, xb);
            #pragma unroll
            for (int n = 0; n < 8; ++n) {
                const int j    = n * 16 + mfr;
                const int slot = (ks * 4 + quad) ^ (j & 7);
                const bf16x8 bv = *(const bf16x8*)(Bs + j * 128 + slot * 8);
                acc[n] = __builtin_amdgcn_mfma_f32_16x16x32_bf16(
                    av, bv, acc[n], 0, 0, 0);
            }
        }
    }

    // ---- epilogue: reduce tx over quads, + tx[i] + ty[j], NT fp32 stores
    txp += __shfl_xor(txp, 16);
    txp += __shfl_xor(txp, 32);
    // lane now holds full tx for local row mfr

    float tyv[8];
    #pragma unroll
    for (int n = 0; n < 8; ++n)
        tyv[n] = tys[n * 16 + mfr];

    float* outB = out + ((size_t)b << 20)
                + (size_t)(is * 128 + w * 16) * TT + jt * 128;
    #pragma unroll
    for (int r = 0; r < 4; ++r) {
        const int row = quad * 4 + r;         // local row 0..15
        const float trow = __shfl(txp, (lane & 48) | row);
        #pragma unroll
        for (int n = 0; n < 8; ++n)
            __builtin_nontemporal_store(
                acc[n][r] + trow + tyv[n],
                &outB[(size_t)row * TT + n * 16 + mfr]);
    }
}

extern "C" void kernel_launch(void* const* d_in, const int* in_sizes, int n_in,
                              void* d_out, int out_size, void* d_ws, size_t ws_size,
                              hipStream_t stream)
{
    const float* x  = (const float*)d_in[0];
    const float* y  = (const float*)d_in[1];
    const float* WS = (const float*)d_in[2];
    float* out = (float*)d_out;
    (void)d_ws; (void)ws_size;   // no workspace needed — fully fused

    fused_kernel<<<dim3(1024), dim3(512), 0, stream>>>(x, y, WS, out);
}